// Round 5
// baseline (232.399 us; speedup 1.0000x reference)
//
#include <hip/hip_runtime.h>
#include <hip/hip_bf16.h>

// LoRALinear: y = x @ W^T + b + 1.0 * ((x @ A^T) @ B^T)
// W_eff = W + B@A (bf16, ws[0..2MB)).
// Fused GEMM 256x256x64, 8-phase counted-vmcnt (T1+T2+T3+T4+T5).
// A (x fp32) reg-staged with fused fp32->bf16 cvt, DOUBLE reg-set pipeline:
//   p1/p2 of tile t: issue A(t+2) global loads (set t&1)
//   p3/p4 of tile t: cvt+ds_write A(t+1) (set (t-1)&1, loaded during t-1)
//   -> 6-phase issue->consume gap covers HBM latency.
// B via global_load_lds staged 2 tiles ahead (region dead after p2).

typedef __bf16 bf16;
typedef bf16 bf16x8 __attribute__((ext_vector_type(8)));
typedef float f32x4 __attribute__((ext_vector_type(4)));

constexpr int K_DIM = 1024;
constexpr int N_DIM = 1024;
constexpr int M_DIM = 8 * 4096;
constexpr int NT = K_DIM / 64;  // 16 K-tiles
constexpr float SCALING = 16.0f / 16.0f;

// ---------------- W_eff = W + B@A, cast to bf16 ----------------
__global__ __launch_bounds__(256) void weff_kernel(
    const float* __restrict__ W, const float* __restrict__ A,
    const float* __restrict__ B, bf16* __restrict__ weff) {
  const int o = blockIdx.x;
  const int tid = threadIdx.x;
  float br[16];
#pragma unroll
  for (int r = 0; r < 16; ++r) br[r] = B[o * 16 + r];
#pragma unroll
  for (int j = 0; j < 4; ++j) {
    const int k = tid + j * 256;
    float s = W[o * K_DIM + k];
#pragma unroll
    for (int r = 0; r < 16; ++r) s += SCALING * br[r] * A[r * K_DIM + k];
    weff[o * K_DIM + k] = (bf16)s;
  }
}

// ---------------- fused 8-phase 256x256 GEMM ----------------
__device__ __forceinline__ void async16(const void* g, void* l) {
  __builtin_amdgcn_global_load_lds(
      (const __attribute__((address_space(1))) void*)g,
      (__attribute__((address_space(3))) void*)l, 16, 0, 0);
}
#define BAR() __builtin_amdgcn_s_barrier()
#define LGKM0()                                        \
  do {                                                 \
    asm volatile("s_waitcnt lgkmcnt(0)" ::: "memory"); \
    __builtin_amdgcn_sched_barrier(0);                 \
  } while (0)
#define VMW(n) asm volatile("s_waitcnt vmcnt(" #n ")" ::: "memory")
#define MFMA(d, a, b) d = __builtin_amdgcn_mfma_f32_16x16x32_bf16(a, b, d, 0, 0, 0)

// LDS (bf16 elems): buf c at c*32768; A [0,16384), B [16384,32768).
// Row = 64 bf16 = 8 chunks of 16 B; stored chunk s holds global chunk s^(row&7).

__global__ __launch_bounds__(512, 2) void gemm8f(
    const float* __restrict__ Xf, const bf16* __restrict__ Wf,
    const float* __restrict__ bias, float* __restrict__ Y) {
  __shared__ __align__(16) bf16 smem[65536];  // 128 KiB

  const int tid = threadIdx.x;
  const int lane = tid & 63;
  const int wid = tid >> 6;
  const int wm = wid >> 2;  // 0..1
  const int wn = wid & 3;   // 0..3
  const int l15 = lane & 15;
  const int lq = lane >> 4;

  // XCD-aware bijective swizzle (512 % 8 == 0)
  const int bid = blockIdx.x;
  const int wgid = (bid & 7) * 64 + (bid >> 3);
  const int bm = wgid >> 2;  // 0..127
  const int bn = wgid & 3;   // 0..3
  const long m0 = (long)bm * 256;
  const int n0 = bn * 256;

  // ---- B staging (global_load_lds, pre-swizzled source) ----
  const int srow = tid >> 3;               // 0..63
  const int gch = (tid & 7) ^ (srow & 7);  // inverse of read swizzle
  const bf16* wsrc = Wf + (long)(n0 + srow) * K_DIM + gch * 8;
  auto stageB = [&](int tt, int h) {
    bf16* dst = smem + (tt & 1) * 32768 + 16384 + h * 8192 + tid * 8;
    const bf16* s = wsrc + (long)h * 128 * K_DIM + tt * 64;
    async16(s, dst);
    async16(s + 64 * K_DIM, dst + 4096);
  };

  // ---- A staging (reg-staged fp32 -> bf16, swizzled ds_write) ----
  const int arow = tid >> 2;  // 0..127
  const int acp = tid & 3;    // chunk pair: global chunks 2acp, 2acp+1
  const int ar7 = arow & 7;
  const int aslot0 = (2 * acp) ^ ar7;
  const int aslot1 = (2 * acp + 1) ^ ar7;
  const float* asrc = Xf + (m0 + arow) * K_DIM + acp * 16;

  auto loadAh = [&](int tt, int h, f32x4 (&r)[4]) {
    const float* s = asrc + (long)h * 128 * K_DIM + tt * 64;
#pragma unroll
    for (int i = 0; i < 4; ++i) r[i] = *(const f32x4*)(s + i * 4);
  };
  auto writeA = [&](int tt, int h, f32x4 (&r)[4]) {
    bf16* dst = smem + (tt & 1) * 32768 + h * 8192 + arow * 64;
    bf16x8 c0, c1;
#pragma unroll
    for (int j = 0; j < 4; ++j) {
      c0[j] = (bf16)r[0][j];
      c0[4 + j] = (bf16)r[1][j];
      c1[j] = (bf16)r[2][j];
      c1[4 + j] = (bf16)r[3][j];
    }
    *(bf16x8*)(dst + aslot0 * 8) = c0;
    *(bf16x8*)(dst + aslot1 * 8) = c1;
  };

  // fragment read offsets (XOR bank swizzle); kk=1 -> elem offset ^32
  const int key = l15 & 7;
  const int ck0 = lq ^ key;
  const int eA = (wm * 128 + l15) * 64 + ck0 * 8;
  const int eB = (wn * 64 + l15) * 64 + ck0 * 8;

  f32x4 acc[8][4] = {};

  // double A-register sets (tile-parity alternation, all static-indexed)
  f32x4 s0h0[4], s0h1[4], s1h0[4], s1h1[4];

  // ---- prologue: B(0),B(1) async; A(0),A(1) loaded+written eagerly ----
  stageB(0, 0); stageB(0, 1); stageB(1, 0); stageB(1, 1);
  loadAh(0, 0, s0h0); loadAh(0, 1, s0h1);
  writeA(0, 0, s0h0); writeA(0, 1, s0h1);
  loadAh(1, 0, s0h0); loadAh(1, 1, s0h1);
  writeA(1, 0, s0h0); writeA(1, 1, s0h1);
  VMW(0);
  asm volatile("s_waitcnt lgkmcnt(0)" ::: "memory");
  BAR();

  // tile body: loads A(t+2) into ld*, writes A(t+1) from wr* (loaded at t-1)
  auto tile = [&](int t, f32x4 (&ld0)[4], f32x4 (&ld1)[4], f32x4 (&wr0)[4],
                  f32x4 (&wr1)[4]) {
    const bf16* Ab = smem + (t & 1) * 32768;
    const bf16* Bb = Ab + 16384;
    bf16x8 B0[4], B1[4];
    {  // p1: (m0-3, kk0); issue A(t+2) h0 loads
      bf16x8 A[4];
#pragma unroll
      for (int i = 0; i < 4; ++i) A[i] = *(const bf16x8*)(Ab + eA + i * 1024);
#pragma unroll
      for (int i = 0; i < 4; ++i) B0[i] = *(const bf16x8*)(Bb + eB + i * 1024);
      if (t < NT - 2) loadAh(t + 2, 0, ld0);
      BAR();
      LGKM0();
      __builtin_amdgcn_s_setprio(1);
#pragma unroll
      for (int m = 0; m < 4; ++m)
#pragma unroll
        for (int n = 0; n < 4; ++n) MFMA(acc[m][n], A[m], B0[n]);
      __builtin_amdgcn_s_setprio(0);
      BAR();
    }
    {  // p2: (m0-3, kk1); issue A(t+2) h1 loads
      bf16x8 A[4];
#pragma unroll
      for (int i = 0; i < 4; ++i)
        A[i] = *(const bf16x8*)(Ab + (eA ^ 32) + i * 1024);
#pragma unroll
      for (int i = 0; i < 4; ++i)
        B1[i] = *(const bf16x8*)(Bb + (eB ^ 32) + i * 1024);
      if (t < NT - 2) loadAh(t + 2, 1, ld1);
      BAR();
      LGKM0();
      __builtin_amdgcn_s_setprio(1);
#pragma unroll
      for (int m = 0; m < 4; ++m)
#pragma unroll
        for (int n = 0; n < 4; ++n) MFMA(acc[m][n], A[m], B1[n]);
      __builtin_amdgcn_s_setprio(0);
      BAR();
    }
    {  // p3: (m4-7, kk0); stage B(t+2) lo; write A(t+1) h0 (from tile t-1)
      bf16x8 A[4];
#pragma unroll
      for (int i = 0; i < 4; ++i)
        A[i] = *(const bf16x8*)(Ab + eA + 4096 + i * 1024);
      if (t < NT - 2) stageB(t + 2, 0);
      if (t >= 1 && t < NT - 1) writeA(t + 1, 0, wr0);
      BAR();
      LGKM0();
      __builtin_amdgcn_s_setprio(1);
#pragma unroll
      for (int m = 0; m < 4; ++m)
#pragma unroll
        for (int n = 0; n < 4; ++n) MFMA(acc[4 + m][n], A[m], B0[n]);
      __builtin_amdgcn_s_setprio(0);
      BAR();
    }
    {  // p4: (m4-7, kk1); stage B(t+2) hi; write A(t+1) h1; counted boundary
      bf16x8 A[4];
#pragma unroll
      for (int i = 0; i < 4; ++i)
        A[i] = *(const bf16x8*)(Ab + (eA ^ 32) + 4096 + i * 1024);
      if (t < NT - 2) stageB(t + 2, 1);
      if (t >= 1 && t < NT - 1) writeA(t + 1, 1, wr1);
      BAR();
      LGKM0();
      __builtin_amdgcn_s_setprio(1);
#pragma unroll
      for (int m = 0; m < 4; ++m)
#pragma unroll
        for (int n = 0; n < 4; ++n) MFMA(acc[4 + m][n], A[m], B1[n]);
      __builtin_amdgcn_s_setprio(0);
      // boundary: B(t+1) (issued tile t-1) must retire; this tile's 12
      // (A(t+2) 8 + B(t+2) 4) may stay in flight.
      if (t < NT - 2) {
        VMW(12);
      } else if (t == NT - 2) {
        VMW(0);
      }
      BAR();
    }
  };

  for (int t = 0; t < NT; t += 2) {
    tile(t, s0h0, s0h1, s1h0, s1h1);      // even: load set0, write set1
    tile(t + 1, s1h0, s1h1, s0h0, s0h1);  // odd: load set1, write set0
  }

  // epilogue: C/D layout col = lane&15, row = lq*4 + reg
  const long crow0 = m0 + wm * 128 + lq * 4;
  const int ccol0 = n0 + wn * 64 + l15;
  float bn4[4];
#pragma unroll
  for (int n = 0; n < 4; ++n) bn4[n] = bias[ccol0 + n * 16];
#pragma unroll
  for (int m = 0; m < 8; ++m)
#pragma unroll
    for (int n = 0; n < 4; ++n) {
      const int col = ccol0 + n * 16;
#pragma unroll
      for (int i = 0; i < 4; ++i)
        Y[(crow0 + m * 16 + i) * N_DIM + col] = acc[m][n][i] + bn4[n];
    }
}

extern "C" void kernel_launch(void* const* d_in, const int* in_sizes, int n_in,
                              void* d_out, int out_size, void* d_ws, size_t ws_size,
                              hipStream_t stream) {
  const float* x = (const float*)d_in[0];
  const float* W = (const float*)d_in[1];
  const float* b = (const float*)d_in[2];
  const float* lA = (const float*)d_in[3];
  const float* lB = (const float*)d_in[4];
  float* y = (float*)d_out;

  bf16* weff = (bf16*)d_ws;  // 2 MB

  weff_kernel<<<dim3(1024), dim3(256), 0, stream>>>(W, lA, lB, weff);

  const int grid = (M_DIM / 256) * (N_DIM / 256);  // 512
  gemm8f<<<dim3(grid), dim3(512), 0, stream>>>(x, weff, b, y);
}

// Round 6
// 117.773 us; speedup vs baseline: 1.9733x; 1.9733x over previous
//
#include <hip/hip_runtime.h>
#include <hip/hip_bf16.h>

// LoRALinear: y = x @ W^T + b + 1.0 * ((x @ A^T) @ B^T)
// W_eff = W + B@A (bf16, ws[0..2MB)).
// Fused GEMM 256x256x64, 8-phase counted-vmcnt (T1+T2+T3+T4+T5).
// A (x fp32) reg-staged with fused fp32->bf16 cvt, SINGLE reg-set pipeline:
//   p3/p4 of tile t: cvt+ds_write A(t+1) (regs loaded at p3/p4 of t-1),
//   then immediately re-issue loads for A(t+2) into the same regs.
//   -> 4-phase issue->consume gap covers HBM latency; no extra VGPRs.
// B via global_load_lds staged 2 tiles ahead (B LDS region dead after p2,
// B fragments held in regs across the tile).

typedef __bf16 bf16;
typedef bf16 bf16x8 __attribute__((ext_vector_type(8)));
typedef float f32x4 __attribute__((ext_vector_type(4)));

constexpr int K_DIM = 1024;
constexpr int N_DIM = 1024;
constexpr int M_DIM = 8 * 4096;
constexpr int NT = K_DIM / 64;  // 16 K-tiles
constexpr float SCALING = 16.0f / 16.0f;

// ---------------- W_eff = W + B@A, cast to bf16 ----------------
__global__ __launch_bounds__(256) void weff_kernel(
    const float* __restrict__ W, const float* __restrict__ A,
    const float* __restrict__ B, bf16* __restrict__ weff) {
  const int o = blockIdx.x;
  const int tid = threadIdx.x;
  float br[16];
#pragma unroll
  for (int r = 0; r < 16; ++r) br[r] = B[o * 16 + r];
#pragma unroll
  for (int j = 0; j < 4; ++j) {
    const int k = tid + j * 256;
    float s = W[o * K_DIM + k];
#pragma unroll
    for (int r = 0; r < 16; ++r) s += SCALING * br[r] * A[r * K_DIM + k];
    weff[o * K_DIM + k] = (bf16)s;
  }
}

// ---------------- fused 8-phase 256x256 GEMM ----------------
__device__ __forceinline__ void async16(const void* g, void* l) {
  __builtin_amdgcn_global_load_lds(
      (const __attribute__((address_space(1))) void*)g,
      (__attribute__((address_space(3))) void*)l, 16, 0, 0);
}
#define BAR() __builtin_amdgcn_s_barrier()
#define LGKM0()                                        \
  do {                                                 \
    asm volatile("s_waitcnt lgkmcnt(0)" ::: "memory"); \
    __builtin_amdgcn_sched_barrier(0);                 \
  } while (0)
#define VMW(n) asm volatile("s_waitcnt vmcnt(" #n ")" ::: "memory")
#define MFMA(d, a, b) d = __builtin_amdgcn_mfma_f32_16x16x32_bf16(a, b, d, 0, 0, 0)

// LDS (bf16 elems): buf c at c*32768; A [0,16384), B [16384,32768).
// Row = 64 bf16 = 8 chunks of 16 B; stored chunk s holds global chunk s^(row&7).

__global__ __launch_bounds__(512, 2) void gemm8f(
    const float* __restrict__ Xf, const bf16* __restrict__ Wf,
    const float* __restrict__ bias, float* __restrict__ Y) {
  __shared__ __align__(16) bf16 smem[65536];  // 128 KiB

  const int tid = threadIdx.x;
  const int lane = tid & 63;
  const int wid = tid >> 6;
  const int wm = wid >> 2;  // 0..1
  const int wn = wid & 3;   // 0..3
  const int l15 = lane & 15;
  const int lq = lane >> 4;

  // XCD-aware bijective swizzle (512 % 8 == 0)
  const int bid = blockIdx.x;
  const int wgid = (bid & 7) * 64 + (bid >> 3);
  const int bm = wgid >> 2;  // 0..127
  const int bn = wgid & 3;   // 0..3
  const long m0 = (long)bm * 256;
  const int n0 = bn * 256;

  // ---- B staging (global_load_lds, pre-swizzled source) ----
  const int srow = tid >> 3;               // 0..63
  const int gch = (tid & 7) ^ (srow & 7);  // inverse of read swizzle
  const bf16* wsrc = Wf + (long)(n0 + srow) * K_DIM + gch * 8;
  auto stageB = [&](int tt, int h) {
    bf16* dst = smem + (tt & 1) * 32768 + 16384 + h * 8192 + tid * 8;
    const bf16* s = wsrc + (long)h * 128 * K_DIM + tt * 64;
    async16(s, dst);
    async16(s + 64 * K_DIM, dst + 4096);
  };

  // ---- A staging (reg-staged fp32 -> bf16, swizzled ds_write) ----
  const int arow = tid >> 2;  // 0..127
  const int acp = tid & 3;    // chunk pair: global chunks 2acp, 2acp+1
  const int ar7 = arow & 7;
  const int aslot0 = (2 * acp) ^ ar7;
  const int aslot1 = (2 * acp + 1) ^ ar7;
  const float* asrc = Xf + (m0 + arow) * K_DIM + acp * 16;

  f32x4 rA0[4], rA1[4];  // single in-flight A set (halves 0/1)
  auto loadA0 = [&](int tt) {
    const float* s = asrc + tt * 64;
#pragma unroll
    for (int i = 0; i < 4; ++i) rA0[i] = *(const f32x4*)(s + i * 4);
  };
  auto loadA1 = [&](int tt) {
    const float* s = asrc + (long)128 * K_DIM + tt * 64;
#pragma unroll
    for (int i = 0; i < 4; ++i) rA1[i] = *(const f32x4*)(s + i * 4);
  };
  auto writeA0 = [&](int tt) {  // cvt+write from rA0
    bf16* dst = smem + (tt & 1) * 32768 + arow * 64;
    bf16x8 c0, c1;
#pragma unroll
    for (int j = 0; j < 4; ++j) {
      c0[j] = (bf16)rA0[0][j];
      c0[4 + j] = (bf16)rA0[1][j];
      c1[j] = (bf16)rA0[2][j];
      c1[4 + j] = (bf16)rA0[3][j];
    }
    *(bf16x8*)(dst + aslot0 * 8) = c0;
    *(bf16x8*)(dst + aslot1 * 8) = c1;
  };
  auto writeA1 = [&](int tt) {  // cvt+write from rA1
    bf16* dst = smem + (tt & 1) * 32768 + 8192 + arow * 64;
    bf16x8 c0, c1;
#pragma unroll
    for (int j = 0; j < 4; ++j) {
      c0[j] = (bf16)rA1[0][j];
      c0[4 + j] = (bf16)rA1[1][j];
      c1[j] = (bf16)rA1[2][j];
      c1[4 + j] = (bf16)rA1[3][j];
    }
    *(bf16x8*)(dst + aslot0 * 8) = c0;
    *(bf16x8*)(dst + aslot1 * 8) = c1;
  };

  // fragment read offsets (XOR bank swizzle); kk=1 -> elem offset ^32
  const int key = l15 & 7;
  const int ck0 = lq ^ key;
  const int eA = (wm * 128 + l15) * 64 + ck0 * 8;
  const int eB = (wn * 64 + l15) * 64 + ck0 * 8;

  f32x4 acc[8][4] = {};

  // ---- prologue ----
  // order matters (FIFO): loadA(0) first so its cvt-wait doesn't drain B.
  loadA0(0); loadA1(0);
  stageB(0, 0); stageB(0, 1); stageB(1, 0); stageB(1, 1);
  writeA0(0); writeA1(0);        // compiler waits vmcnt to retire loadA(0) only
  loadA0(1); loadA1(1);          // rA now holds A(1), consumed at tile 0 p3/p4
  VMW(12);                       // retire B(0); keep B(1)+loadA(1) in flight
  asm volatile("s_waitcnt lgkmcnt(0)" ::: "memory");
  BAR();

  for (int t = 0; t < NT; ++t) {
    const bf16* Ab = smem + (t & 1) * 32768;
    const bf16* Bb = Ab + 16384;
    bf16x8 B0[4], B1[4];
    {  // p1: (m0-3, kk0)
      bf16x8 A[4];
#pragma unroll
      for (int i = 0; i < 4; ++i) A[i] = *(const bf16x8*)(Ab + eA + i * 1024);
#pragma unroll
      for (int i = 0; i < 4; ++i) B0[i] = *(const bf16x8*)(Bb + eB + i * 1024);
      BAR();
      LGKM0();
      __builtin_amdgcn_s_setprio(1);
#pragma unroll
      for (int m = 0; m < 4; ++m)
#pragma unroll
        for (int n = 0; n < 4; ++n) MFMA(acc[m][n], A[m], B0[n]);
      __builtin_amdgcn_s_setprio(0);
      BAR();
    }
    {  // p2: (m0-3, kk1)
      bf16x8 A[4];
#pragma unroll
      for (int i = 0; i < 4; ++i)
        A[i] = *(const bf16x8*)(Ab + (eA ^ 32) + i * 1024);
#pragma unroll
      for (int i = 0; i < 4; ++i)
        B1[i] = *(const bf16x8*)(Bb + (eB ^ 32) + i * 1024);
      BAR();
      LGKM0();
      __builtin_amdgcn_s_setprio(1);
#pragma unroll
      for (int m = 0; m < 4; ++m)
#pragma unroll
        for (int n = 0; n < 4; ++n) MFMA(acc[m][n], A[m], B1[n]);
      __builtin_amdgcn_s_setprio(0);
      BAR();
    }
    {  // p3: (m4-7, kk0); stage B(t+2) lo; write A(t+1) h0; reload rA0<-A(t+2)
      bf16x8 A[4];
#pragma unroll
      for (int i = 0; i < 4; ++i)
        A[i] = *(const bf16x8*)(Ab + eA + 4096 + i * 1024);
      if (t < NT - 2) stageB(t + 2, 0);
      if (t < NT - 1) writeA0(t + 1);  // waits loadA0(t+1), retires B(t+1)lo-
      if (t < NT - 2) loadA0(t + 2);   // WAR safe: issued after cvt reads
      BAR();
      LGKM0();
      __builtin_amdgcn_s_setprio(1);
#pragma unroll
      for (int m = 0; m < 4; ++m)
#pragma unroll
        for (int n = 0; n < 4; ++n) MFMA(acc[4 + m][n], A[m], B0[n]);
      __builtin_amdgcn_s_setprio(0);
      BAR();
    }
    {  // p4: (m4-7, kk1); stage B(t+2) hi; write A(t+1) h1; reload rA1
      bf16x8 A[4];
#pragma unroll
      for (int i = 0; i < 4; ++i)
        A[i] = *(const bf16x8*)(Ab + (eA ^ 32) + 4096 + i * 1024);
      if (t < NT - 2) stageB(t + 2, 1);
      if (t < NT - 1) writeA1(t + 1);
      if (t < NT - 2) loadA1(t + 2);
      BAR();
      LGKM0();
      __builtin_amdgcn_s_setprio(1);
#pragma unroll
      for (int m = 0; m < 4; ++m)
#pragma unroll
        for (int n = 0; n < 4; ++n) MFMA(acc[4 + m][n], A[m], B1[n]);
      __builtin_amdgcn_s_setprio(0);
      // boundary: B(t+1) already retired by writeA's cvt-dependency waits
      // (FIFO: B(t+1) older than loadA(t+1)); this tile's 12 newest
      // (stageB(t+2) 4 + loadA(t+2) 8) may stay in flight.
      if (t < NT - 2) {
        VMW(12);
      } else if (t == NT - 2) {
        VMW(0);
      }
      BAR();
    }
  }

  // epilogue: C/D layout col = lane&15, row = lq*4 + reg
  const long crow0 = m0 + wm * 128 + lq * 4;
  const int ccol0 = n0 + wn * 64 + l15;
  float bn4[4];
#pragma unroll
  for (int n = 0; n < 4; ++n) bn4[n] = bias[ccol0 + n * 16];
#pragma unroll
  for (int m = 0; m < 8; ++m)
#pragma unroll
    for (int n = 0; n < 4; ++n) {
      const int col = ccol0 + n * 16;
#pragma unroll
      for (int i = 0; i < 4; ++i)
        Y[(crow0 + m * 16 + i) * N_DIM + col] = acc[m][n][i] + bn4[n];
    }
}

extern "C" void kernel_launch(void* const* d_in, const int* in_sizes, int n_in,
                              void* d_out, int out_size, void* d_ws, size_t ws_size,
                              hipStream_t stream) {
  const float* x = (const float*)d_in[0];
  const float* W = (const float*)d_in[1];
  const float* b = (const float*)d_in[2];
  const float* lA = (const float*)d_in[3];
  const float* lB = (const float*)d_in[4];
  float* y = (float*)d_out;

  bf16* weff = (bf16*)d_ws;  // 2 MB

  weff_kernel<<<dim3(1024), dim3(256), 0, stream>>>(W, lA, lB, weff);

  const int grid = (M_DIM / 256) * (N_DIM / 256);  // 512
  gemm8f<<<dim3(grid), dim3(512), 0, stream>>>(x, weff, b, y);
}